// Round 12
// baseline (393.225 us; speedup 1.0000x reference)
//
#include <hip/hip_runtime.h>
#include <math.h>

typedef unsigned short u16;
typedef unsigned int u32;
typedef short short8 __attribute__((ext_vector_type(8)));
typedef float f32x4 __attribute__((ext_vector_type(4)));

#define NB 64
#define CCH 512
#define HW 256

// ---- bf16 helpers (bit-level, RNE) ----
__device__ __forceinline__ u16 f2bf(float f) {
    union { float f; u32 u; } x; x.f = f;
    u32 r = x.u + 0x7fffu + ((x.u >> 16) & 1u);
    return (u16)(r >> 16);
}
__device__ __forceinline__ float bf2f(u16 b) {
    union { u32 u; float f; } x; x.u = ((u32)b) << 16;
    return x.f;
}
__device__ __forceinline__ void gload_lds16(const u16* g, u16* l) {
    __builtin_amdgcn_global_load_lds((const __attribute__((address_space(1))) u32*)g,
                                     (__attribute__((address_space(3))) u32*)l, 16, 0, 0);
}

// ---------------------------------------------------------------------------
__global__ __launch_bounds__(256) void zero_borders(u16* __restrict__ pad) {
    const int n = blockIdx.x, t = threadIdx.x;
    short8 z = (short8){0,0,0,0,0,0,0,0};
    for (int idx = t; idx < 68 * 64; idx += 256) {
        int cell = idx >> 6, ch = idx & 63;
        int hh, ww;
        if (cell < 18)      { hh = 0;          ww = cell; }
        else if (cell < 36) { hh = 17;         ww = cell - 18; }
        else if (cell < 52) { hh = cell - 35;  ww = 0; }
        else                { hh = cell - 51;  ww = 17; }
        *(short8*)(pad + ((size_t)((n * 18 + hh) * 18 + ww)) * 512 + ch * 8) = z;
    }
}

// ---------------------------------------------------------------------------
// NCHW fp32 -> padded pixel-major bf16 [n][18][18][512] (interior only)
// ---------------------------------------------------------------------------
__global__ __launch_bounds__(256) void prep_x(const float* __restrict__ x, u16* __restrict__ pad) {
    __shared__ float tl[64][65];
    const int n = blockIdx.z, c0 = blockIdx.y * 64, p0 = blockIdx.x * 64;
    const int t = threadIdx.x;
    {
        const int cc = t >> 2, ps = (t & 3) * 16;
#pragma unroll
        for (int i = 0; i < 4; ++i) {
            float4 v4 = *(const float4*)(x + (((size_t)(n * 512 + c0 + cc)) << 8) + p0 + ps + i * 4);
            tl[cc][ps + i * 4 + 0] = v4.x;
            tl[cc][ps + i * 4 + 1] = v4.y;
            tl[cc][ps + i * 4 + 2] = v4.z;
            tl[cc][ps + i * 4 + 3] = v4.w;
        }
    }
    __syncthreads();
    {
        const int pp = t >> 2, cs = (t & 3) * 16;
        short8 o0, o1;
#pragma unroll
        for (int i = 0; i < 8; ++i) o0[i] = (short)f2bf(tl[cs + i][pp]);
#pragma unroll
        for (int i = 0; i < 8; ++i) o1[i] = (short)f2bf(tl[cs + 8 + i][pp]);
        const int p = p0 + pp, h = p >> 4, wcol = p & 15;
        u16* dst = pad + ((size_t)((n * 18 + h + 1) * 18 + wcol + 1)) * 512 + c0 + cs;
        *(short8*)(dst + 0) = o0;
        *(short8*)(dst + 8) = o1;
    }
}

// ---------------------------------------------------------------------------
// weights fp32 [co][ci][3][3] -> bf16 Wt[sel][tap][co][ci]
// ---------------------------------------------------------------------------
__global__ __launch_bounds__(256) void prep_w(
    const float* __restrict__ Wq, const float* __restrict__ Wk,
    const float* __restrict__ Wv, const float* __restrict__ Wc,
    u16* __restrict__ Wt)
{
    __shared__ float lw[4608];
    const int co = blockIdx.x, sel = blockIdx.y, t = threadIdx.x;
    const float* Ws = (sel == 0) ? Wq : (sel == 1) ? Wk : (sel == 2) ? Wv : Wc;
#pragma unroll
    for (int i = 0; i < 18; ++i) lw[t + i * 256] = Ws[(size_t)co * 4608 + t + i * 256];
    __syncthreads();
    for (int tap = 0; tap < 9; ++tap)
#pragma unroll
        for (int hh = 0; hh < 2; ++hh) {
            int ci = t + hh * 256;
            Wt[(((size_t)(sel * 9 + tap)) << 18) + (co << 9) + ci] = f2bf(lw[ci * 9 + tap]);
        }
}

// ---------------------------------------------------------------------------
// Fused QKV conv3x3 implicit GEMM — wide wave tile 128x96, NO VGPR cap.
// (r8 retry: r8's regression was __launch_bounds__(512,2) capping VGPR at 128
//  -> 192-float acc spilled to scratch. This build lets the allocator use
//  ~240 VGPR: acc 192 + fb 24 + streamed fa + addresses; 2 waves/SIMD.)
// M=16384 (p-major), N=1536, K=4608. BM=256, BN=384, BK=32. 8 waves 2Mx4N,
// wave tile 128x96: 48 MFMA / (8 A + 6 B) ds_reads per tile -> per-CU
// MFMA 1862 cyc vs LDS ~1570 -> MFMA-bound even under serialization.
// Schedule = r4-verified: one barrier + counted vmcnt(5)/vmcnt(0) per tile.
// Rotation swizzle (zero conflicts): stage cl=((l&3)-(l>>3))&3,
// frag phys chunk = ((l>>4)+(l>>1))&3.
// Grid 256 = 64 Mtiles x 4 cobases, bijective XCD swizzle.
// ---------------------------------------------------------------------------
__global__ __launch_bounds__(512) void qkv_wide(
    const u16* __restrict__ pad, const u16* __restrict__ Wt,
    u16* __restrict__ q, u16* __restrict__ k, u16* __restrict__ v)
{
    __shared__ short As[3][8192];    // 256 rows x 32 k, 16KB each
    __shared__ short Bs[3][12288];   // 384 rows x 32 k, 24KB each
    const int t = threadIdx.x;
    const int l = t & 63;
    const int wid = t >> 6;          // 0..7
    const int wm = wid >> 2, wn = wid & 3;

    const int o = blockIdx.x;        // 256 blocks
    const int wg = (o & 7) * 32 + (o >> 3);
    const int imbase = (wg >> 2) * 256;
    const int cobase = (wg & 3) * 384;

    const int cl = ((l & 3) - ((l >> 3) & 3)) & 3;
    int imoffA[2], woffB[3];
#pragma unroll
    for (int rr = 0; rr < 2; ++rr) {                       // A units 0..15
        const int chunk = wid * 2 + rr;
        const int imrow = imbase + chunk * 16 + (l >> 2);
        const int p = imrow >> 6, n = imrow & 63;
        imoffA[rr] = ((n * 18 + (p >> 4)) * 18 + (p & 15)) * 512 + cl * 8;
    }
#pragma unroll
    for (int rr = 0; rr < 3; ++rr) {                       // B units 0..23
        const int cof = cobase + (wid * 3 + rr) * 16 + (l >> 2);
        const int sel = cof >> 9, co = cof & 511;
        woffB[rr] = sel * 9 * 262144 + co * 512 + cl * 8;
    }

    const int fp = ((l >> 4) + (l >> 1)) & 3;
    const int aoff = (wm * 128 + (l & 15)) * 32 + fp * 8;
    const int boff = (wn * 96 + (l & 15)) * 32 + fp * 8;

    f32x4 acc[8][6];
#pragma unroll
    for (int i = 0; i < 8; ++i)
#pragma unroll
        for (int j = 0; j < 6; ++j) acc[i][j] = (f32x4){0.f, 0.f, 0.f, 0.f};

    auto STAGE = [&](int kt, int s) {
        const int tap = kt >> 4;
        const int ashift = ((tap / 3) * 18 + (tap % 3)) * 512 + (kt & 15) * 32;
        const int bshift = tap * 262144 + (kt & 15) * 32;
#pragma unroll
        for (int rr = 0; rr < 2; ++rr)
            gload_lds16(pad + imoffA[rr] + ashift, (u16*)(&As[s][0] + (wid * 2 + rr) * 512));
#pragma unroll
        for (int rr = 0; rr < 3; ++rr)
            gload_lds16(Wt + woffB[rr] + bshift, (u16*)(&Bs[s][0] + (wid * 3 + rr) * 512));
    };

    STAGE(0, 0);
    STAGE(1, 1);

    int s0 = 0;
    short8 fb[6];
#pragma unroll 1
    for (int kt = 0; kt < 144; ++kt) {
        const int s2 = (s0 == 0) ? 2 : s0 - 1;    // (kt+2)%3
        const short* Ab = &As[s0][0];
        const short* Bb = &Bs[s0][0];

        if (kt >= 143) asm volatile("s_waitcnt vmcnt(0)" ::: "memory");
        else           asm volatile("s_waitcnt vmcnt(5)" ::: "memory");
        __builtin_amdgcn_sched_barrier(0);
        __builtin_amdgcn_s_barrier();
        __builtin_amdgcn_sched_barrier(0);

#pragma unroll
        for (int j = 0; j < 6; ++j) fb[j] = *(const short8*)(Bb + boff + j * 512);

        if (kt < 142) STAGE(kt + 2, s2);

        __builtin_amdgcn_s_setprio(1);
#pragma unroll
        for (int i = 0; i < 8; ++i) {
            short8 fa = *(const short8*)(Ab + aoff + i * 512);
#pragma unroll
            for (int j = 0; j < 6; ++j)
                acc[i][j] = __builtin_amdgcn_mfma_f32_16x16x32_bf16(fa, fb[j], acc[i][j], 0, 0, 0);
        }
        __builtin_amdgcn_s_setprio(0);

        s0 = (s0 == 2) ? 0 : s0 + 1;
    }

    // epilogue: C layout col = lane&15, row = (lane>>4)*4 + reg
#pragma unroll
    for (int j = 0; j < 6; ++j) {
        const int colb = cobase + wn * 96 + j * 16;
        u16* op = ((colb >> 9) == 0) ? q : (((colb >> 9) == 1) ? k : v);
        op += (colb & 511) + (l & 15);
#pragma unroll
        for (int i = 0; i < 8; ++i) {
            const int row = imbase + wm * 128 + i * 16 + (l >> 4) * 4;
#pragma unroll
            for (int r = 0; r < 4; ++r)
                op[(size_t)(row + r) * 512] = f2bf(acc[i][j][r]);
        }
    }
}

// ---------------------------------------------------------------------------
// Final conv3x3 + residual — 4-wave / 2-blocks-per-CU (r7/r8 verified).
// ---------------------------------------------------------------------------
__global__ __launch_bounds__(256, 2) void cres_mfma4(
    const u16* __restrict__ pad, const u16* __restrict__ WtC,
    const float* __restrict__ xres, float* __restrict__ out)
{
    __shared__ short As[3][4096];   // 128 co x 32
    __shared__ short Bs[3][4096];   // 128 imrows x 32
    const int t = threadIdx.x;
    const int l = t & 63;
    const int wid = t >> 6;          // 0..3
    const int wm = wid >> 1, wn = wid & 1;

    const int o = blockIdx.x;        // 512 blocks
    const int cobase = (o & 3) * 128;
    const int imbase = (o >> 2) * 128;   // imrow = n*256 + p

    const int cl = ((l & 3) - ((l >> 3) & 3)) & 3;
    int woffA[2], imoffB[2];
#pragma unroll
    for (int rr = 0; rr < 2; ++rr) {
        const int co = cobase + (wid * 2 + rr) * 16 + (l >> 2);
        woffA[rr] = co * 512 + cl * 8;
        const int imrow = imbase + (wid * 2 + rr) * 16 + (l >> 2);
        const int n = imrow >> 8, p = imrow & 255;
        imoffB[rr] = ((n * 18 + (p >> 4)) * 18 + (p & 15)) * 512 + cl * 8;
    }

    const int fp = ((l >> 4) + (l >> 1)) & 3;
    const int aoff = (wm * 64 + (l & 15)) * 32 + fp * 8;
    const int boff = (wn * 64 + (l & 15)) * 32 + fp * 8;

    f32x4 acc[4][4];
#pragma unroll
    for (int i = 0; i < 4; ++i)
#pragma unroll
        for (int j = 0; j < 4; ++j) acc[i][j] = (f32x4){0.f, 0.f, 0.f, 0.f};

    auto STAGE = [&](int kt, int s) {
        const int tap = kt >> 4;
        const int ashift = tap * 262144 + (kt & 15) * 32;
        const int bshift = ((tap / 3) * 18 + (tap % 3)) * 512 + (kt & 15) * 32;
#pragma unroll
        for (int rr = 0; rr < 2; ++rr) {
            gload_lds16(WtC + woffA[rr] + ashift, (u16*)(&As[s][0] + (wid * 2 + rr) * 512));
            gload_lds16(pad + imoffB[rr] + bshift, (u16*)(&Bs[s][0] + (wid * 2 + rr) * 512));
        }
    };

    STAGE(0, 0);
    STAGE(1, 1);

    int s0 = 0;
    short8 fa[4], fb[4];
#pragma unroll 1
    for (int kt = 0; kt < 144; ++kt) {
        const int s2 = (s0 == 0) ? 2 : s0 - 1;
        const short* Ab = &As[s0][0];
        const short* Bb = &Bs[s0][0];

        if (kt >= 143) asm volatile("s_waitcnt vmcnt(0)" ::: "memory");
        else           asm volatile("s_waitcnt vmcnt(4)" ::: "memory");
        __builtin_amdgcn_sched_barrier(0);
        __builtin_amdgcn_s_barrier();
        __builtin_amdgcn_sched_barrier(0);

#pragma unroll
        for (int i = 0; i < 4; ++i) fa[i] = *(const short8*)(Ab + aoff + i * 512);
#pragma unroll
        for (int j = 0; j < 4; ++j) fb[j] = *(const short8*)(Bb + boff + j * 512);

        if (kt < 142) STAGE(kt + 2, s2);

        __builtin_amdgcn_s_setprio(1);
#pragma unroll
        for (int i = 0; i < 4; ++i)
#pragma unroll
            for (int j = 0; j < 4; ++j)
                acc[i][j] = __builtin_amdgcn_mfma_f32_16x16x32_bf16(fa[i], fb[j], acc[i][j], 0, 0, 0);
        __builtin_amdgcn_s_setprio(0);

        s0 = (s0 == 2) ? 0 : s0 + 1;
    }

#pragma unroll
    for (int i = 0; i < 4; ++i)
#pragma unroll
        for (int j = 0; j < 4; ++j)
#pragma unroll
            for (int r = 0; r < 4; ++r) {
                int co = cobase + wm * 64 + i * 16 + (l >> 4) * 4 + r;
                int imrow = imbase + wn * 64 + j * 16 + (l & 15);
                int n = imrow >> 8, p = imrow & 255;
                size_t addr = (((size_t)(n * 512 + co)) << 8) + p;
                out[addr] = acc[i][j][r] + xres[addr];
            }
}

// ---------------------------------------------------------------------------
// attention per pixel: MFMA QK^T (direct-global frags) + fp32 PV + GN partials
// (r11-verified)
// ---------------------------------------------------------------------------
__global__ __launch_bounds__(256) void attn_kernel(
    const u16* __restrict__ qT, const u16* __restrict__ kT, u16* vvT,
    float* __restrict__ gnp)
{
    const int p = blockIdx.x;
    const int t = threadIdx.x;
    const int l = t & 63;
    const int w = t >> 6;
    __shared__ float attb[64][68];
    __shared__ float vs[8448];   // vs[m*132 + c]
    const size_t pb = (size_t)p * (NB * CCH);

    // ---- QK^T via MFMA ----
    const u16* qbase = qT + pb + (size_t)(w * 16 + (l & 15)) * 512 + (l >> 4) * 8;
    const u16* kbase = kT + pb + (size_t)(l & 15) * 512 + (l >> 4) * 8;
    f32x4 s[4];
#pragma unroll
    for (int j = 0; j < 4; ++j) s[j] = (f32x4){0.f, 0.f, 0.f, 0.f};
#pragma unroll 4
    for (int kc = 0; kc < 16; ++kc) {
        short8 a = *(const short8*)(qbase + kc * 32);
#pragma unroll
        for (int j = 0; j < 4; ++j) {
            short8 b = *(const short8*)(kbase + (size_t)j * 16 * 512 + kc * 32);
            s[j] = __builtin_amdgcn_mfma_f32_16x16x32_bf16(a, b, s[j], 0, 0, 0);
        }
    }

    const float SCALE = 0.0441941738241592f;  // 1/sqrt(512)
#pragma unroll
    for (int r = 0; r < 4; ++r) {
        float mx = fmaxf(fmaxf(s[0][r], s[1][r]), fmaxf(s[2][r], s[3][r]));
#pragma unroll
        for (int mask = 1; mask < 16; mask <<= 1) mx = fmaxf(mx, __shfl_xor(mx, mask));
        float e[4]; float sm = 0.f;
#pragma unroll
        for (int j = 0; j < 4; ++j) { e[j] = __expf((s[j][r] - mx) * SCALE); sm += e[j]; }
#pragma unroll
        for (int mask = 1; mask < 16; mask <<= 1) sm += __shfl_xor(sm, mask);
        float inv = 1.f / sm;
        const int row = w * 16 + (l >> 4) * 4 + r;
#pragma unroll
        for (int j = 0; j < 4; ++j) attb[row][j * 16 + (l & 15)] = e[j] * inv;
    }
    __syncthreads();

    // ---- PV (fp32) + GN partial accumulation ----
    const int ng2 = t >> 3, cg = t & 7;
    const int nn0 = ng2 * 2, cb = cg * 16;
    float rsum[2] = {0.f, 0.f}, rss[2] = {0.f, 0.f};
    for (int ct4 = 0; ct4 < 4; ++ct4) {
        const int c0 = ct4 * 128;
#pragma unroll
        for (int sld = 0; sld < 4; ++sld) {
            int f = t + sld * 256;
            int m = f >> 4, c8 = (f & 15) * 8;
            short8 vv = *(const short8*)(vvT + pb + (size_t)m * CCH + c0 + c8);
#pragma unroll
            for (int e = 0; e < 8; ++e) vs[m * 132 + c8 + e] = bf2f((u16)vv[e]);
        }
        __syncthreads();
        float acc2[2][16];
#pragma unroll
        for (int i = 0; i < 2; ++i)
#pragma unroll
            for (int j = 0; j < 16; ++j) acc2[i][j] = 0.f;
#pragma unroll 4
        for (int m = 0; m < 64; ++m) {
            float a0 = attb[nn0][m], a1 = attb[nn0 + 1][m];
#pragma unroll
            for (int k4 = 0; k4 < 4; ++k4) {
                float4 v4 = *(const float4*)&vs[m * 132 + cb + k4 * 4];
                acc2[0][k4 * 4 + 0] = fmaf(a0, v4.x, acc2[0][k4 * 4 + 0]);
                acc2[0][k4 * 4 + 1] = fmaf(a0, v4.y, acc2[0][k4 * 4 + 1]);
                acc2[0][k4 * 4 + 2] = fmaf(a0, v4.z, acc2[0][k4 * 4 + 2]);
                acc2[0][k4 * 4 + 3] = fmaf(a0, v4.w, acc2[0][k4 * 4 + 3]);
                acc2[1][k4 * 4 + 0] = fmaf(a1, v4.x, acc2[1][k4 * 4 + 0]);
                acc2[1][k4 * 4 + 1] = fmaf(a1, v4.y, acc2[1][k4 * 4 + 1]);
                acc2[1][k4 * 4 + 2] = fmaf(a1, v4.z, acc2[1][k4 * 4 + 2]);
                acc2[1][k4 * 4 + 3] = fmaf(a1, v4.w, acc2[1][k4 * 4 + 3]);
            }
        }
#pragma unroll
        for (int i = 0; i < 2; ++i)
#pragma unroll
            for (int j = 0; j < 16; ++j) {
                float x = acc2[i][j];
                rsum[i] += x;
                rss[i] = fmaf(x, x, rss[i]);
                vvT[pb + (size_t)(nn0 + i) * CCH + c0 + cb + j] = f2bf(x);
            }
        __syncthreads();
    }

#pragma unroll
    for (int i = 0; i < 2; ++i) {
#pragma unroll
        for (int mask = 1; mask < 8; mask <<= 1) {
            rsum[i] += __shfl_xor(rsum[i], mask);
            rss[i]  += __shfl_xor(rss[i],  mask);
        }
    }
    if (cg == 0) {
#pragma unroll
        for (int i = 0; i < 2; ++i) {
            gnp[((size_t)p * 64 + nn0 + i) * 2 + 0] = rsum[i];
            gnp[((size_t)p * 64 + nn0 + i) * 2 + 1] = rss[i];
        }
    }
}

// ---------------------------------------------------------------------------
// GN apply: reduce per-pixel partials (gnp[p][n][2]) + affine + ReLU -> ypad
// ---------------------------------------------------------------------------
__global__ __launch_bounds__(256) void gn_part2(
    const u16* __restrict__ virtT, const float* __restrict__ gnp,
    const float* __restrict__ gamma, const float* __restrict__ beta,
    u16* __restrict__ ypad)
{
    const int n = blockIdx.x >> 2, qr = blockIdx.x & 3, t = threadIdx.x;
    __shared__ float sg[512], sb[512];
    for (int i = t; i < 512; i += 256) { sg[i] = gamma[i]; sb[i] = beta[i]; }

    float sum = gnp[((size_t)t * 64 + n) * 2 + 0];
    float ss  = gnp[((size_t)t * 64 + n) * 2 + 1];
#pragma unroll
    for (int off = 32; off > 0; off >>= 1) {
        sum += __shfl_down(sum, off);
        ss  += __shfl_down(ss, off);
    }
    __shared__ float rs[4], rss[4], stats[2];
    const int wid = t >> 6, lane = t & 63;
    if (lane == 0) { rs[wid] = sum; rss[wid] = ss; }
    __syncthreads();
    if (t == 0) {
        float S = rs[0] + rs[1] + rs[2] + rs[3];
        float SS = rss[0] + rss[1] + rss[2] + rss[3];
        float mu = S * (1.f / 131072.f);
        float var = SS * (1.f / 131072.f) - mu * mu;
        stats[0] = mu;
        stats[1] = rsqrtf(var + 1e-5f);
    }
    __syncthreads();
    const float mu = stats[0], rstd = stats[1];

#pragma unroll 4
    for (int it = 0; it < 16; ++it) {
        int f = t + it * 256;
        int p = qr * 64 + (f >> 6), cc = (f & 63) * 8;
        short8 vv = *(const short8*)(virtT + ((size_t)(p * 64 + n)) * 512 + cc);
        short8 ov;
#pragma unroll
        for (int e = 0; e < 8; ++e) {
            float x = (bf2f((u16)vv[e]) - mu) * rstd;
            x = fmaf(x, sg[cc + e], sb[cc + e]);
            ov[e] = (short)f2bf(fmaxf(x, 0.f));
        }
        int h = p >> 4, wcol = p & 15;
        *(short8*)(ypad + ((size_t)((n * 18 + h + 1) * 18 + wcol + 1)) * 512 + cc) = ov;
    }
}

// ---------------------------------------------------------------------------
extern "C" void kernel_launch(void* const* d_in, const int* in_sizes, int n_in,
                              void* d_out, int out_size, void* d_ws, size_t ws_size,
                              hipStream_t stream)
{
    const float* x     = (const float*)d_in[0];
    const float* Wq    = (const float*)d_in[1];
    const float* Wk    = (const float*)d_in[2];
    const float* Wv    = (const float*)d_in[3];
    const float* Wc    = (const float*)d_in[4];
    const float* gamma = (const float*)d_in[5];
    const float* beta  = (const float*)d_in[6];
    float* out = (float*)d_out;

    // workspace (u16 units): pad | Wt | q | k | v  (~90.4 MB total)
    u16* pad = (u16*)d_ws;
    u16* Wt  = pad + 10616832;
    u16* q   = Wt + 9437184;
    u16* k   = q + 8388608;
    u16* v   = k + 8388608;   // virt written in place after PV
    float* gnp = (float*)Wt;  // Wq-section of Wt, dead after qkv

    zero_borders<<<dim3(64), dim3(256), 0, stream>>>(pad);
    prep_x<<<dim3(4, 8, 64), dim3(256), 0, stream>>>(x, pad);
    prep_w<<<dim3(512, 4), dim3(256), 0, stream>>>(Wq, Wk, Wv, Wc, Wt);

    qkv_wide<<<dim3(256), dim3(512), 0, stream>>>(pad, Wt, q, k, v);
    attn_kernel<<<dim3(256), dim3(256), 0, stream>>>(q, k, v, gnp);
    gn_part2<<<dim3(256), dim3(256), 0, stream>>>(v, gnp, gamma, beta, pad);
    cres_mfma4<<<dim3(512), dim3(256), 0, stream>>>(pad, Wt + 3 * 2359296, x, out);
}

// Round 13
// 369.433 us; speedup vs baseline: 1.0644x; 1.0644x over previous
//
#include <hip/hip_runtime.h>
#include <math.h>

typedef unsigned short u16;
typedef unsigned int u32;
typedef short short8 __attribute__((ext_vector_type(8)));
typedef short short4v __attribute__((ext_vector_type(4)));
typedef float f32x4 __attribute__((ext_vector_type(4)));

#define NB 64
#define CCH 512
#define HW 256

// ---- bf16 helpers (bit-level, RNE) ----
__device__ __forceinline__ u16 f2bf(float f) {
    union { float f; u32 u; } x; x.f = f;
    u32 r = x.u + 0x7fffu + ((x.u >> 16) & 1u);
    return (u16)(r >> 16);
}
__device__ __forceinline__ float bf2f(u16 b) {
    union { u32 u; float f; } x; x.u = ((u32)b) << 16;
    return x.f;
}
__device__ __forceinline__ void gload_lds16(const u16* g, u16* l) {
    __builtin_amdgcn_global_load_lds((const __attribute__((address_space(1))) u32*)g,
                                     (__attribute__((address_space(3))) u32*)l, 16, 0, 0);
}

// ---------------------------------------------------------------------------
__global__ __launch_bounds__(256) void zero_borders(u16* __restrict__ pad) {
    const int n = blockIdx.x, t = threadIdx.x;
    short8 z = (short8){0,0,0,0,0,0,0,0};
    for (int idx = t; idx < 68 * 64; idx += 256) {
        int cell = idx >> 6, ch = idx & 63;
        int hh, ww;
        if (cell < 18)      { hh = 0;          ww = cell; }
        else if (cell < 36) { hh = 17;         ww = cell - 18; }
        else if (cell < 52) { hh = cell - 35;  ww = 0; }
        else                { hh = cell - 51;  ww = 17; }
        *(short8*)(pad + ((size_t)((n * 18 + hh) * 18 + ww)) * 512 + ch * 8) = z;
    }
}

// ---------------------------------------------------------------------------
// NCHW fp32 -> padded pixel-major bf16 [n][18][18][512] (interior only)
// ---------------------------------------------------------------------------
__global__ __launch_bounds__(256) void prep_x(const float* __restrict__ x, u16* __restrict__ pad) {
    __shared__ float tl[64][65];
    const int n = blockIdx.z, c0 = blockIdx.y * 64, p0 = blockIdx.x * 64;
    const int t = threadIdx.x;
    {
        const int cc = t >> 2, ps = (t & 3) * 16;
#pragma unroll
        for (int i = 0; i < 4; ++i) {
            float4 v4 = *(const float4*)(x + (((size_t)(n * 512 + c0 + cc)) << 8) + p0 + ps + i * 4);
            tl[cc][ps + i * 4 + 0] = v4.x;
            tl[cc][ps + i * 4 + 1] = v4.y;
            tl[cc][ps + i * 4 + 2] = v4.z;
            tl[cc][ps + i * 4 + 3] = v4.w;
        }
    }
    __syncthreads();
    {
        const int pp = t >> 2, cs = (t & 3) * 16;
        short8 o0, o1;
#pragma unroll
        for (int i = 0; i < 8; ++i) o0[i] = (short)f2bf(tl[cs + i][pp]);
#pragma unroll
        for (int i = 0; i < 8; ++i) o1[i] = (short)f2bf(tl[cs + 8 + i][pp]);
        const int p = p0 + pp, h = p >> 4, wcol = p & 15;
        u16* dst = pad + ((size_t)((n * 18 + h + 1) * 18 + wcol + 1)) * 512 + c0 + cs;
        *(short8*)(dst + 0) = o0;
        *(short8*)(dst + 8) = o1;
    }
}

// ---------------------------------------------------------------------------
// weights fp32 [co][ci][3][3] -> bf16 Wt[sel][tap][co][ci]
// ---------------------------------------------------------------------------
__global__ __launch_bounds__(256) void prep_w(
    const float* __restrict__ Wq, const float* __restrict__ Wk,
    const float* __restrict__ Wv, const float* __restrict__ Wc,
    u16* __restrict__ Wt)
{
    __shared__ float lw[4608];
    const int co = blockIdx.x, sel = blockIdx.y, t = threadIdx.x;
    const float* Ws = (sel == 0) ? Wq : (sel == 1) ? Wk : (sel == 2) ? Wv : Wc;
#pragma unroll
    for (int i = 0; i < 18; ++i) lw[t + i * 256] = Ws[(size_t)co * 4608 + t + i * 256];
    __syncthreads();
    for (int tap = 0; tap < 9; ++tap)
#pragma unroll
        for (int hh = 0; hh < 2; ++hh) {
            int ci = t + hh * 256;
            Wt[(((size_t)(sel * 9 + tap)) << 18) + (co << 9) + ci] = f2bf(lw[ci * 9 + tap]);
        }
}

// ---------------------------------------------------------------------------
// Fused QKV conv3x3 implicit GEMM — r4-verified 242us config.
// Only change vs r11: the v-third of the epilogue writes TRANSPOSED per-pixel
// layout vT2[p][c][n] (one short4 store per frag: 4 acc regs = consecutive n),
// feeding attention's MFMA PV directly.
// ---------------------------------------------------------------------------
__global__ __launch_bounds__(512, 1) void qkv_mfma8(
    const u16* __restrict__ pad, const u16* __restrict__ Wt,
    u16* __restrict__ q, u16* __restrict__ k, u16* __restrict__ v)
{
    __shared__ short As[3][8192];   // [256 rows][32 k], 16KB each
    __shared__ short Bs[3][6144];   // [192 rows][32 k], 12KB each
    const int t = threadIdx.x;
    const int l = t & 63;
    const int wid = t >> 6;
    const int wm = wid >> 2, wn = wid & 3;

    // XCD-bijective block swizzle (512 blocks, 8 XCDs)
    const int o = blockIdx.x;
    const int wg = (o & 7) * 64 + (o >> 3);
    const int imbase = (wg >> 3) * 256;
    const int cobase = (wg & 7) * 192;

    const int cl = ((l & 3) - ((l >> 3) & 3)) & 3;
    int imoffA[2], woffB[2];
#pragma unroll
    for (int rr = 0; rr < 2; ++rr) {
        const int chunk = wid * 2 + rr;
        const int imrow = imbase + chunk * 16 + (l >> 2);
        const int p = imrow >> 6, n = imrow & 63;
        imoffA[rr] = ((n * 18 + (p >> 4)) * 18 + (p & 15)) * 512 + cl * 8;
        const int cof = cobase + chunk * 16 + (l >> 2);
        const int sel = cof >> 9, co = cof & 511;
        woffB[rr] = sel * 9 * 262144 + co * 512 + cl * 8;   // used if wid<6
    }

    const int fp = ((l >> 4) + (l >> 1)) & 3;
    const int aoff = (wm * 128 + (l & 15)) * 32 + fp * 8;
    const int boff = (wn * 48 + (l & 15)) * 32 + fp * 8;

    f32x4 acc[8][3];
#pragma unroll
    for (int i = 0; i < 8; ++i)
#pragma unroll
        for (int j = 0; j < 3; ++j) acc[i][j] = (f32x4){0.f, 0.f, 0.f, 0.f};

    auto STAGE_A = [&](int kt, int s) {
        const int tap = kt >> 4;
        const int shift = ((tap / 3) * 18 + (tap % 3)) * 512 + (kt & 15) * 32;
#pragma unroll
        for (int rr = 0; rr < 2; ++rr)
            gload_lds16(pad + imoffA[rr] + shift, (u16*)(&As[s][0] + (wid * 2 + rr) * 512));
    };
    auto STAGE_B = [&](int kt, int s) {
        if (wid < 6) {
            const int tap = kt >> 4;
            const int shift = tap * 262144 + (kt & 15) * 32;
#pragma unroll
            for (int rr = 0; rr < 2; ++rr)
                gload_lds16(Wt + woffB[rr] + shift, (u16*)(&Bs[s][0] + (wid * 2 + rr) * 512));
        }
    };

    STAGE_A(0, 0); STAGE_B(0, 0);
    STAGE_A(1, 1); STAGE_B(1, 1);

    int s0 = 0;
    short8 fa[8], fb[3];
#pragma unroll 1
    for (int kt = 0; kt < 144; ++kt) {
        const int s2 = (s0 == 0) ? 2 : s0 - 1;    // (kt+2)%3
        const short* Ab = &As[s0][0];
        const short* Bb = &Bs[s0][0];

        if (kt >= 143) {
            asm volatile("s_waitcnt vmcnt(0)" ::: "memory");
        } else if (wid < 6) {
            asm volatile("s_waitcnt vmcnt(4)" ::: "memory");
        } else {
            asm volatile("s_waitcnt vmcnt(2)" ::: "memory");
        }
        __builtin_amdgcn_sched_barrier(0);
        __builtin_amdgcn_s_barrier();
        __builtin_amdgcn_sched_barrier(0);

#pragma unroll
        for (int j = 0; j < 3; ++j) fb[j] = *(const short8*)(Bb + boff + j * 512);
#pragma unroll
        for (int i = 0; i < 8; ++i) fa[i] = *(const short8*)(Ab + aoff + i * 512);

        if (kt < 142) { STAGE_A(kt + 2, s2); STAGE_B(kt + 2, s2); }

        __builtin_amdgcn_s_setprio(1);
#pragma unroll
        for (int i = 0; i < 8; ++i)
#pragma unroll
            for (int j = 0; j < 3; ++j)
                acc[i][j] = __builtin_amdgcn_mfma_f32_16x16x32_bf16(fa[i], fb[j], acc[i][j], 0, 0, 0);
        __builtin_amdgcn_s_setprio(0);

        s0 = (s0 == 2) ? 0 : s0 + 1;
    }

    // epilogue: C layout col = lane&15, row = (lane>>4)*4 + reg
#pragma unroll
    for (int j = 0; j < 3; ++j) {
        const int colb = cobase + wn * 48 + j * 16;
        const int sel = colb >> 9;
        if (sel == 2) {
            // v third: write transposed vT2[p][c][n], one short4 per frag
            const int c = (colb & 511) + (l & 15);
#pragma unroll
            for (int i = 0; i < 8; ++i) {
                const int rowb = imbase + wm * 128 + i * 16 + (l >> 4) * 4;
                const int pp = rowb >> 6, nb = rowb & 63;
                short4v sv;
#pragma unroll
                for (int r = 0; r < 4; ++r) sv[r] = (short)f2bf(acc[i][j][r]);
                *(short4v*)(v + (size_t)pp * 32768 + (size_t)c * 64 + nb) = sv;
            }
        } else {
            u16* op = (sel == 0) ? q : k;
            op += (colb & 511) + (l & 15);
#pragma unroll
            for (int i = 0; i < 8; ++i) {
                const int row = imbase + wm * 128 + i * 16 + (l >> 4) * 4;
#pragma unroll
                for (int r = 0; r < 4; ++r)
                    op[(size_t)(row + r) * 512] = f2bf(acc[i][j][r]);
            }
        }
    }
}

// ---------------------------------------------------------------------------
// Final conv3x3 + residual — 4-wave / 2-blocks-per-CU (r7/r8 verified).
// ---------------------------------------------------------------------------
__global__ __launch_bounds__(256, 2) void cres_mfma4(
    const u16* __restrict__ pad, const u16* __restrict__ WtC,
    const float* __restrict__ xres, float* __restrict__ out)
{
    __shared__ short As[3][4096];   // 128 co x 32
    __shared__ short Bs[3][4096];   // 128 imrows x 32
    const int t = threadIdx.x;
    const int l = t & 63;
    const int wid = t >> 6;          // 0..3
    const int wm = wid >> 1, wn = wid & 1;

    const int o = blockIdx.x;        // 512 blocks
    const int cobase = (o & 3) * 128;
    const int imbase = (o >> 2) * 128;   // imrow = n*256 + p

    const int cl = ((l & 3) - ((l >> 3) & 3)) & 3;
    int woffA[2], imoffB[2];
#pragma unroll
    for (int rr = 0; rr < 2; ++rr) {
        const int co = cobase + (wid * 2 + rr) * 16 + (l >> 2);
        woffA[rr] = co * 512 + cl * 8;
        const int imrow = imbase + (wid * 2 + rr) * 16 + (l >> 2);
        const int n = imrow >> 8, p = imrow & 255;
        imoffB[rr] = ((n * 18 + (p >> 4)) * 18 + (p & 15)) * 512 + cl * 8;
    }

    const int fp = ((l >> 4) + (l >> 1)) & 3;
    const int aoff = (wm * 64 + (l & 15)) * 32 + fp * 8;
    const int boff = (wn * 64 + (l & 15)) * 32 + fp * 8;

    f32x4 acc[4][4];
#pragma unroll
    for (int i = 0; i < 4; ++i)
#pragma unroll
        for (int j = 0; j < 4; ++j) acc[i][j] = (f32x4){0.f, 0.f, 0.f, 0.f};

    auto STAGE = [&](int kt, int s) {
        const int tap = kt >> 4;
        const int ashift = tap * 262144 + (kt & 15) * 32;
        const int bshift = ((tap / 3) * 18 + (tap % 3)) * 512 + (kt & 15) * 32;
#pragma unroll
        for (int rr = 0; rr < 2; ++rr) {
            gload_lds16(WtC + woffA[rr] + ashift, (u16*)(&As[s][0] + (wid * 2 + rr) * 512));
            gload_lds16(pad + imoffB[rr] + bshift, (u16*)(&Bs[s][0] + (wid * 2 + rr) * 512));
        }
    };

    STAGE(0, 0);
    STAGE(1, 1);

    int s0 = 0;
    short8 fa[4], fb[4];
#pragma unroll 1
    for (int kt = 0; kt < 144; ++kt) {
        const int s2 = (s0 == 0) ? 2 : s0 - 1;
        const short* Ab = &As[s0][0];
        const short* Bb = &Bs[s0][0];

        if (kt >= 143) asm volatile("s_waitcnt vmcnt(0)" ::: "memory");
        else           asm volatile("s_waitcnt vmcnt(4)" ::: "memory");
        __builtin_amdgcn_sched_barrier(0);
        __builtin_amdgcn_s_barrier();
        __builtin_amdgcn_sched_barrier(0);

#pragma unroll
        for (int i = 0; i < 4; ++i) fa[i] = *(const short8*)(Ab + aoff + i * 512);
#pragma unroll
        for (int j = 0; j < 4; ++j) fb[j] = *(const short8*)(Bb + boff + j * 512);

        if (kt < 142) STAGE(kt + 2, s2);

        __builtin_amdgcn_s_setprio(1);
#pragma unroll
        for (int i = 0; i < 4; ++i)
#pragma unroll
            for (int j = 0; j < 4; ++j)
                acc[i][j] = __builtin_amdgcn_mfma_f32_16x16x32_bf16(fa[i], fb[j], acc[i][j], 0, 0, 0);
        __builtin_amdgcn_s_setprio(0);

        s0 = (s0 == 2) ? 0 : s0 + 1;
    }

#pragma unroll
    for (int i = 0; i < 4; ++i)
#pragma unroll
        for (int j = 0; j < 4; ++j)
#pragma unroll
            for (int r = 0; r < 4; ++r) {
                int co = cobase + wm * 64 + i * 16 + (l >> 4) * 4 + r;
                int imrow = imbase + wn * 64 + j * 16 + (l & 15);
                int n = imrow >> 8, p = imrow & 255;
                size_t addr = (((size_t)(n * 512 + co)) << 8) + p;
                out[addr] = acc[i][j][r] + xres[addr];
            }
}

// ---------------------------------------------------------------------------
// attention per pixel, fully MFMA: QK^T (r11-verified, bf16 att out) + MFMA PV
// from vT2[p][c][m] (direct-global B frags). virt written into the dead q slab.
// GN partials from PV accumulators (16-lane shfl + LDS combine).
// ---------------------------------------------------------------------------
__global__ __launch_bounds__(256) void attn_kernel(
    u16* __restrict__ qT, const u16* __restrict__ kT, const u16* __restrict__ vT2,
    float* __restrict__ gnp)
{
    const int p = blockIdx.x;
    const int t = threadIdx.x;
    const int l = t & 63;
    const int w = t >> 6;
    __shared__ u16 attB[64][72];          // bf16 att, +8 pad (2-way max)
    __shared__ float gnw_s[4][64], gnw_q[4][64];
    const size_t pb = (size_t)p * (NB * CCH);

    // ---- QK^T via MFMA (verified r11 structure) ----
    const u16* qbase = qT + pb + (size_t)(w * 16 + (l & 15)) * 512 + (l >> 4) * 8;
    const u16* kbase = kT + pb + (size_t)(l & 15) * 512 + (l >> 4) * 8;
    f32x4 s[4];
#pragma unroll
    for (int j = 0; j < 4; ++j) s[j] = (f32x4){0.f, 0.f, 0.f, 0.f};
#pragma unroll 4
    for (int kc = 0; kc < 16; ++kc) {
        short8 a = *(const short8*)(qbase + kc * 32);
#pragma unroll
        for (int j = 0; j < 4; ++j) {
            short8 b = *(const short8*)(kbase + (size_t)j * 16 * 512 + kc * 32);
            s[j] = __builtin_amdgcn_mfma_f32_16x16x32_bf16(a, b, s[j], 0, 0, 0);
        }
    }

    const float SCALE = 0.0441941738241592f;  // 1/sqrt(512)
#pragma unroll
    for (int r = 0; r < 4; ++r) {
        float mx = fmaxf(fmaxf(s[0][r], s[1][r]), fmaxf(s[2][r], s[3][r]));
#pragma unroll
        for (int mask = 1; mask < 16; mask <<= 1) mx = fmaxf(mx, __shfl_xor(mx, mask));
        float e[4]; float sm = 0.f;
#pragma unroll
        for (int j = 0; j < 4; ++j) { e[j] = __expf((s[j][r] - mx) * SCALE); sm += e[j]; }
#pragma unroll
        for (int mask = 1; mask < 16; mask <<= 1) sm += __shfl_xor(sm, mask);
        float inv = 1.f / sm;
        const int row = w * 16 + (l >> 4) * 4 + r;
#pragma unroll
        for (int j = 0; j < 4; ++j) attB[row][j * 16 + (l & 15)] = f2bf(e[j] * inv);
    }
    __syncthreads();

    // ---- PV via MFMA: virt[n][c] = sum_m att[n][m] * vT2[c][m] ----
    // wave w owns c in [128w, 128w+128) (8 c-tiles). B frag: row=c (l&15),
    // k-elems m = (l>>4)*8 + mf*32. A frag from attB: row=n (l&15), same k.
    const int cb = w * 128;
    const u16* vb = vT2 + (size_t)p * 32768 + (size_t)(cb + (l & 15)) * 64 + (l >> 4) * 8;

#pragma unroll 1
    for (int nt = 0; nt < 4; ++nt) {
        short8 fa0 = *(const short8*)(&attB[nt * 16 + (l & 15)][(l >> 4) * 8]);
        short8 fa1 = *(const short8*)(&attB[nt * 16 + (l & 15)][(l >> 4) * 8 + 32]);
        f32x4 acc[8];
#pragma unroll
        for (int ct = 0; ct < 8; ++ct) acc[ct] = (f32x4){0.f, 0.f, 0.f, 0.f};
#pragma unroll
        for (int ct = 0; ct < 8; ++ct) {
            short8 fb0 = *(const short8*)(vb + ct * 1024);
            short8 fb1 = *(const short8*)(vb + ct * 1024 + 32);
            acc[ct] = __builtin_amdgcn_mfma_f32_16x16x32_bf16(fa0, fb0, acc[ct], 0, 0, 0);
            acc[ct] = __builtin_amdgcn_mfma_f32_16x16x32_bf16(fa1, fb1, acc[ct], 0, 0, 0);
        }
        // store virt (into q slab) + GN partials
        float ps[4] = {0.f, 0.f, 0.f, 0.f}, pq[4] = {0.f, 0.f, 0.f, 0.f};
#pragma unroll
        for (int ct = 0; ct < 8; ++ct) {
            const int c = cb + ct * 16 + (l & 15);
#pragma unroll
            for (int r = 0; r < 4; ++r) {
                float x = acc[ct][r];
                ps[r] += x;
                pq[r] = fmaf(x, x, pq[r]);
                const int n = nt * 16 + (l >> 4) * 4 + r;
                qT[pb + (size_t)n * 512 + c] = f2bf(x);
            }
        }
#pragma unroll
        for (int r = 0; r < 4; ++r) {
#pragma unroll
            for (int mask = 1; mask < 16; mask <<= 1) {
                ps[r] += __shfl_xor(ps[r], mask);
                pq[r] += __shfl_xor(pq[r], mask);
            }
        }
        if ((l & 15) == 0) {
#pragma unroll
            for (int r = 0; r < 4; ++r) {
                const int n = nt * 16 + (l >> 4) * 4 + r;
                gnw_s[w][n] = ps[r];
                gnw_q[w][n] = pq[r];
            }
        }
    }
    __syncthreads();
    if (t < 64) {
        float S = gnw_s[0][t] + gnw_s[1][t] + gnw_s[2][t] + gnw_s[3][t];
        float Q = gnw_q[0][t] + gnw_q[1][t] + gnw_q[2][t] + gnw_q[3][t];
        gnp[((size_t)p * 64 + t) * 2 + 0] = S;
        gnp[((size_t)p * 64 + t) * 2 + 1] = Q;
    }
}

// ---------------------------------------------------------------------------
// GN apply: reduce per-pixel partials (gnp[p][n][2]) + affine + ReLU -> ypad
// virtT now = q slab ([p][n][c], written by attn).
// ---------------------------------------------------------------------------
__global__ __launch_bounds__(256) void gn_part2(
    const u16* __restrict__ virtT, const float* __restrict__ gnp,
    const float* __restrict__ gamma, const float* __restrict__ beta,
    u16* __restrict__ ypad)
{
    const int n = blockIdx.x >> 2, qr = blockIdx.x & 3, t = threadIdx.x;
    __shared__ float sg[512], sb[512];
    for (int i = t; i < 512; i += 256) { sg[i] = gamma[i]; sb[i] = beta[i]; }

    float sum = gnp[((size_t)t * 64 + n) * 2 + 0];
    float ss  = gnp[((size_t)t * 64 + n) * 2 + 1];
#pragma unroll
    for (int off = 32; off > 0; off >>= 1) {
        sum += __shfl_down(sum, off);
        ss  += __shfl_down(ss, off);
    }
    __shared__ float rs[4], rss[4], stats[2];
    const int wid = t >> 6, lane = t & 63;
    if (lane == 0) { rs[wid] = sum; rss[wid] = ss; }
    __syncthreads();
    if (t == 0) {
        float S = rs[0] + rs[1] + rs[2] + rs[3];
        float SS = rss[0] + rss[1] + rss[2] + rss[3];
        float mu = S * (1.f / 131072.f);
        float var = SS * (1.f / 131072.f) - mu * mu;
        stats[0] = mu;
        stats[1] = rsqrtf(var + 1e-5f);
    }
    __syncthreads();
    const float mu = stats[0], rstd = stats[1];

#pragma unroll 4
    for (int it = 0; it < 16; ++it) {
        int f = t + it * 256;
        int p = qr * 64 + (f >> 6), cc = (f & 63) * 8;
        short8 vv = *(const short8*)(virtT + ((size_t)(p * 64 + n)) * 512 + cc);
        short8 ov;
#pragma unroll
        for (int e = 0; e < 8; ++e) {
            float x = (bf2f((u16)vv[e]) - mu) * rstd;
            x = fmaf(x, sg[cc + e], sb[cc + e]);
            ov[e] = (short)f2bf(fmaxf(x, 0.f));
        }
        int h = p >> 4, wcol = p & 15;
        *(short8*)(ypad + ((size_t)((n * 18 + h + 1) * 18 + wcol + 1)) * 512 + cc) = ov;
    }
}

// ---------------------------------------------------------------------------
extern "C" void kernel_launch(void* const* d_in, const int* in_sizes, int n_in,
                              void* d_out, int out_size, void* d_ws, size_t ws_size,
                              hipStream_t stream)
{
    const float* x     = (const float*)d_in[0];
    const float* Wq    = (const float*)d_in[1];
    const float* Wk    = (const float*)d_in[2];
    const float* Wv    = (const float*)d_in[3];
    const float* Wc    = (const float*)d_in[4];
    const float* gamma = (const float*)d_in[5];
    const float* beta  = (const float*)d_in[6];
    float* out = (float*)d_out;

    // workspace (u16 units): pad | Wt | q | k | v  (~90.4 MB total)
    u16* pad = (u16*)d_ws;
    u16* Wt  = pad + 10616832;
    u16* q   = Wt + 9437184;
    u16* k   = q + 8388608;
    u16* v   = k + 8388608;   // vT2[p][c][n]; virt goes into q slab
    float* gnp = (float*)Wt;  // Wq-section of Wt, dead after qkv

    zero_borders<<<dim3(64), dim3(256), 0, stream>>>(pad);
    prep_x<<<dim3(4, 8, 64), dim3(256), 0, stream>>>(x, pad);
    prep_w<<<dim3(512, 4), dim3(256), 0, stream>>>(Wq, Wk, Wv, Wc, Wt);

    qkv_mfma8<<<dim3(512), dim3(512), 0, stream>>>(pad, Wt, q, k, v);
    attn_kernel<<<dim3(256), dim3(256), 0, stream>>>(q, k, v, gnp);
    gn_part2<<<dim3(256), dim3(256), 0, stream>>>(q, gnp, gamma, beta, pad);
    cres_mfma4<<<dim3(512), dim3(256), 0, stream>>>(pad, Wt + 3 * 2359296, x, out);
}